// Round 3
// baseline (127.643 us; speedup 1.0000x reference)
//
#include <hip/hip_runtime.h>

// Problem constants
#define BB   2
#define CIN  256
#define OC3  768
#define NG   4
#define GOC  64
#define C2   32
#define KK   49
#define PP   2304
#define HALF_P 1152

// Guarded Y2 layout: rows -3..50 (54), cols -3..52 at stride 56, 768 ch.
#define RS      56
#define BROWS   54
#define BSTRIDE (BROWS * RS * OC3)          // floats per batch = 2,322,432
#define IOFF    ((3 * RS + 3) * OC3)

// Workspace layout (bytes)
#define Y2_BYTES  (BB * BROWS * RS * OC3 * 4)
#define XT_OFF    Y2_BYTES
#define WT_OFF    (XT_OFF + BB * PP * 512 * 2)

typedef __attribute__((ext_vector_type(8))) short bf16x8;
typedef __attribute__((ext_vector_type(4))) float f32x4;

static __device__ __forceinline__ unsigned short f2bf_rne(float x) {
    unsigned int u = __float_as_uint(x);
    unsigned int r = u + 0x7FFFu + ((u >> 16) & 1u);
    return (unsigned short)(r >> 16);
}
static __device__ __forceinline__ float bf2f(unsigned short h) {
    return __uint_as_float(((unsigned int)h) << 16);
}

// ---------------------------------------------------------------------------
// DPP-based exact xor-lane exchange (VALU pipe). Bit-identical semantics.
// ---------------------------------------------------------------------------
template <int C>
static __device__ __forceinline__ float dppf(float x) {
    return __int_as_float(__builtin_amdgcn_update_dpp(
        0, __float_as_int(x), C, 0xF, 0xF, true));
}
template <int D>
static __device__ __forceinline__ float xor_lane(float x) {
    if constexpr (D == 1)       return dppf<0xB1>(x);
    else if constexpr (D == 2)  return dppf<0x4E>(x);
    else if constexpr (D == 4)  return dppf<0x141>(dppf<0x4E>(dppf<0xB1>(x)));
    else if constexpr (D == 8)  return dppf<0x128>(x);
    else                        return __shfl_xor(x, D, 64);
}
template <int N> struct IC { static constexpr int value = N; };

// ---------------------------------------------------------------------------
// Fused prep kernel (unchanged from r7).
// ---------------------------------------------------------------------------
#define ROW4  (RS * OC3 / 4)       // 10752 float4 per spatial row
#define REG1  (6 * ROW4)           // 6 full guard rows (0,1,2,51,52,53)
#define COLS4 (OC3 / 4)            // 192 float4 per cell

__global__ __launch_bounds__(256) void prep(
    float* __restrict__ Y2,
    const float* __restrict__ W, short* __restrict__ Wt,
    const float* __restrict__ X, short* __restrict__ Xt)
{
    __shared__ float tile[64][65];
    const int bid = blockIdx.x;
    const int t   = threadIdx.x;

    if (bid < 1080) {
        const int idx = (bid % 540) * 256 + t;      // 0 .. 138239
        const int b   = bid / 540;
        float4* Yb = (float4*)(Y2 + (size_t)b * BSTRIDE);
        const float4 z = make_float4(0.f, 0.f, 0.f, 0.f);
        if (idx < REG1) {
            int r6  = idx / ROW4;
            int rem = idx - r6 * ROW4;
            int r   = (r6 < 3) ? r6 : 48 + r6;      // 0,1,2,51,52,53
            Yb[r * ROW4 + rem] = z;
        } else {
            int i2  = idx - REG1;
            int r   = 3 + i2 / (8 * COLS4);         // 3..50
            int rem = i2 - (r - 3) * (8 * COLS4);
            int cg  = rem / COLS4;
            int c   = (cg < 3) ? cg : 48 + cg;      // 0,1,2,51..55
            int ch4 = rem - cg * COLS4;
            Yb[(r * RS + c) * COLS4 + ch4] = z;
        }
    } else if (bid < 1848) {
        int tt = (bid - 1080) * 256 + t;            // 0 .. 196607
        int o = tt >> 8, c = tt & 255;
        float v = W[tt];
        unsigned short hi = f2bf_rne(v);
        unsigned short lo = f2bf_rne(v - bf2f(hi));
        Wt[(size_t)o * 512 + c]       = (short)hi;
        Wt[(size_t)o * 512 + 256 + c] = (short)lo;
    } else {
        const int blk = bid - 1848;                 // 0 .. 287
        const int p0  = (blk % 36) * 64;
        const int c0  = ((blk / 36) & 3) * 64;
        const int b   = blk / 144;

        const float* Xb = X + (size_t)b * CIN * PP;
        #pragma unroll
        for (int r = 0; r < 16; ++r) {
            int idx = r * 256 + t;
            int c = idx >> 6, p = idx & 63;
            tile[c][p] = Xb[(size_t)(c0 + c) * PP + p0 + p];
        }
        __syncthreads();
        short* Xo = Xt + (size_t)b * PP * 512;
        #pragma unroll
        for (int r = 0; r < 16; ++r) {
            int idx = r * 256 + t;
            int p = idx >> 6, c = idx & 63;
            float v = tile[c][p];
            unsigned short hi = f2bf_rne(v);
            unsigned short lo = f2bf_rne(v - bf2f(hi));
            size_t base = (size_t)(p0 + p) * 512 + c0 + c;
            Xo[base]       = (short)hi;
            Xo[base + 256] = (short)lo;
        }
    }
}

// ---------------------------------------------------------------------------
// Kernel 1: conv as split-bf16 MFMA GEMM (unchanged).
// ---------------------------------------------------------------------------
#define LDA 40   // shorts per LDS row (32 + 8 pad)

__global__ __launch_bounds__(256, 4) void conv_mfma(
    const short* __restrict__ Wt,   // (768, 512)
    const short* __restrict__ Xt,   // (B, 2304, 512)
    float* __restrict__ Y2)
{
    __shared__ short As[64 * LDA];   // [o][k]
    __shared__ short Bs[64 * LDA];   // [p][k]

    const int tid = threadIdx.x;
    const int bn  = blockIdx.x;       // p tile (36)
    const int bm  = blockIdx.y;       // o tile (12)
    const int b   = blockIdx.z;
    const int om0 = bm * 64, pn0 = bn * 64;

    const int lane = tid & 63, w = tid >> 6;
    const int oq = (w & 1) * 32, pq = (w >> 1) * 32;
    const int ln15 = lane & 15, q = lane >> 4;

    const int  lrow  = (tid & 127) >> 1;    // 0..63
    const int  lsoff = (tid & 1) * 16;      // 0 or 16 shorts
    const bool isA   = tid < 128;
    const short* gA = Wt + (size_t)(om0 + lrow) * 512 + lsoff;
    const short* gB = Xt + (size_t)b * PP * 512 + (size_t)(pn0 + lrow) * 512 + lsoff;
    const short* gsrc = isA ? gA : gB;
    short* ldst = (isA ? As : Bs) + lrow * LDA + lsoff;

    f32x4 acc[2][2] = {};

    for (int k0 = 0; k0 < 768; k0 += 32) {
        const int wk = (k0 < 256) ? k0 : k0 - 256;   // W: hi, hi, lo
        const int xk = (k0 < 512) ? k0 : k0 - 512;   // X: hi, lo, hi
        const int kk = isA ? wk : xk;
        uint4 v0 = *(const uint4*)(gsrc + kk);
        uint4 v1 = *(const uint4*)(gsrc + kk + 8);
        __syncthreads();
        *(uint4*)ldst       = v0;
        *(uint4*)(ldst + 8) = v1;
        __syncthreads();

        bf16x8 af[2], bf[2];
        #pragma unroll
        for (int i = 0; i < 2; ++i) {
            af[i] = *(const bf16x8*)&As[(oq + i * 16 + ln15) * LDA + q * 8];
            bf[i] = *(const bf16x8*)&Bs[(pq + i * 16 + ln15) * LDA + q * 8];
        }
        #pragma unroll
        for (int i = 0; i < 2; ++i)
            #pragma unroll
            for (int j = 0; j < 2; ++j)
                acc[i][j] = __builtin_amdgcn_mfma_f32_16x16x32_bf16(
                    af[i], bf[j], acc[i][j], 0, 0, 0);
    }

    // D[m=o][n=p]: lane = col p (ln15), rows o = q*4..q*4+3 contiguous
    float* Yb = Y2 + (size_t)b * BSTRIDE + IOFF;
    #pragma unroll
    for (int i = 0; i < 2; ++i) {
        #pragma unroll
        for (int j = 0; j < 2; ++j) {
            int o = om0 + oq + i * 16 + q * 4;
            int p = pn0 + pq + j * 16 + ln15;
            int h = p / 48, ww = p - h * 48;
            *(f32x4*)&Yb[(size_t)(h * RS + ww) * OC3 + o] = acc[i][j];
        }
    }
}

// ---------------------------------------------------------------------------
// Kernel 2: attention. One wave per (b,g,p'). XCD-swizzled.
// r9: V-accumulation vectorized. Lane = (channel-quad cq=lane>>2, tap-phase
// tq=lane&3); 13 float4 loads (taps tq+4j) replace 49 scalar loads; per-tap
// attention weight via ds_swizzle (pattern (lane&3)|4j) + one shfl_xor(32)
// to cross the half-wave boundary, replacing 49 readlanes. Tap 48 is
// exec-masked to tq==0 (taps 49..51 would read poisoned memory; their att
// is exactly 0). Final tap-class reduce via DPP xor1/xor2.
// ---------------------------------------------------------------------------
struct TagH { static constexpr bool value = true;  };
struct TagW { static constexpr bool value = false; };

// doff for V tap t (compile-time)
static __host__ __device__ constexpr int vdoff(int t) {
    return ((t / 7 - 3) * RS + (t % 7 - 3)) * OC3;
}

__global__ __launch_bounds__(256, 6) void attn_kernel(
    const float* __restrict__ Y2,
    const float* __restrict__ rpe_h,  // (4,1,7,1,32)
    const float* __restrict__ rpe_w,  // (4,1,1,7,32)
    float* __restrict__ out)          // (B, 256, 48, 48)
{
    __shared__ float xpose[4][65];

    const int tid  = threadIdx.x;
    const int lane = tid & 63;
    const int w    = tid >> 6;
    const int bx     = blockIdx.x;
    const int wblock = (bx & 7) * 576 + (bx >> 3);
    const int wid    = wblock * 4 + w;
    const int pq   = wid % PP;
    const int g    = (wid / PP) & (NG - 1);
    const int b    = wid / (PP * NG);
    const int ph   = pq / 48;
    const int pw   = pq - ph * 48;

    const float* Yb = Y2 + (size_t)b * BSTRIDE + IOFF;

    const float qv = Yb[(size_t)(ph * RS + pw) * OC3 + g * GOC + lane];

    const int t   = (pq >= HALF_P) ? 1 : 0;
    const int qpr = pq - t * HALF_P;
    const int p0  = 2 * qpr;
    const int ph0 = p0 / 48;
    const int pw0 = p0 - ph0 * 48;
    const int g2  = 2 * g + t;
    const bool use_h = (g2 < NG);
    const int  kch   = use_h ? (CIN + g2 * GOC) : (CIN + (g2 - NG) * GOC + C2);
    const float* rb  = use_h ? (rpe_h + g2 * 7 * C2) : (rpe_w + (g2 - NG) * 7 * C2);

    const int  c  = lane & 31;
    const bool hi = (lane >= 32);

    const float R0 = rb[0 * C2 + c], R1 = rb[1 * C2 + c], R2 = rb[2 * C2 + c],
                R3 = rb[3 * C2 + c], R4 = rb[4 * C2 + c], R5 = rb[5 * C2 + c],
                R6 = rb[6 * C2 + c];

    const float* kb = Yb + (size_t)(ph0 * RS + pw0) * OC3 + kch + c;

    auto rget = [&](int idx) -> float {
        return idx == 0 ? R0 : idx == 1 ? R1 : idx == 2 ? R2 :
               idx == 3 ? R3 : idx == 4 ? R4 : idx == 5 ? R5 : R6;
    };

    auto tree = [&](auto tag) -> float {
        constexpr bool UH = decltype(tag)::value;
        auto chunkprod = [&](int l) -> float {
            int m0 = 2 * l,     h10 = (m0 >= KK), k0 = m0 - KK * h10;
            int m1 = 2 * l + 1, h11 = (m1 >= KK), k1 = m1 - KK * h11;
            int i0 = k0 / 7, j0 = k0 % 7, i1 = k1 / 7, j1 = k1 % 7;
            int d0 = ((i0 - 3) * RS + (h10 + j0 - 3)) * OC3;
            int d1 = ((i1 - 3) * RS + (h11 + j1 - 3)) * OC3;
            float kv = kb[hi ? d1 : d0];
            float ra = UH ? rget(i0) : rget(j0);
            float rc = UH ? rget(i1) : rget(j1);
            kv += hi ? rc : ra;
            return qv * kv;
        };
        auto val = [&](int jj) -> float {
            if (2 * jj >= KK) return 0.f;
            float pa = chunkprod(2 * jj);
            float pb = (2 * jj + 1 < KK) ? chunkprod(2 * jj + 1) : 0.f;
            float u  = (lane & 1) ? pb : pa;
            float ww = (lane & 1) ? pa : pb;
            return u + xor_lane<1>(ww);
        };
        auto comb = [&](auto dc, float x, float y) -> float {
            constexpr int d = decltype(dc)::value;
            float u  = (lane & d) ? y : x;
            float ww = (lane & d) ? x : y;
            return u + xor_lane<d>(ww);
        };
        float acc32[2];
        #pragma unroll
        for (int a = 0; a < 2; ++a) {
            float acc16[2];
            #pragma unroll
            for (int bq = 0; bq < 2; ++bq) {
                float acc8[2];
                #pragma unroll
                for (int cq2 = 0; cq2 < 2; ++cq2) {
                    float acc4t[2];
                    #pragma unroll
                    for (int dq = 0; dq < 2; ++dq) {
                        float acc2[2];
                        #pragma unroll
                        for (int eq = 0; eq < 2; ++eq)
                            acc2[eq] = val(a * 16 + bq * 8 + cq2 * 4 + dq * 2 + eq);
                        acc4t[dq] = comb(IC<2>{}, acc2[0], acc2[1]);
                    }
                    acc8[cq2] = comb(IC<4>{}, acc4t[0], acc4t[1]);
                }
                acc16[bq] = comb(IC<8>{}, acc8[0], acc8[1]);
            }
            acc32[a] = comb(IC<16>{}, acc16[0], acc16[1]);
        }
        return comb(IC<32>{}, acc32[0], acc32[1]);
    };

    const float logit = use_h ? tree(TagH{}) : tree(TagW{});

    float mx = logit;
    mx = fmaxf(mx, xor_lane<1>(mx));
    mx = fmaxf(mx, xor_lane<2>(mx));
    mx = fmaxf(mx, xor_lane<4>(mx));
    mx = fmaxf(mx, xor_lane<8>(mx));
    mx = fmaxf(mx, xor_lane<16>(mx));
    mx = fmaxf(mx, xor_lane<32>(mx));
    float e = (lane < KK) ? __expf(logit - mx) : 0.f;
    float ssum = e;
    ssum += xor_lane<1>(ssum);
    ssum += xor_lane<2>(ssum);
    ssum += xor_lane<4>(ssum);
    ssum += xor_lane<8>(ssum);
    ssum += xor_lane<16>(ssum);
    ssum += xor_lane<32>(ssum);
    const float att = e / ssum;           // lane = tap (0 for lane >= 49)

    // ---- r9 vectorized V accumulation ----
    const float attB = __shfl_xor(att, 32, 64);   // lane L holds att[L^32]
    const int  cq = lane >> 2;            // channel quad 0..15
    const int  tq = lane & 3;             // tap phase 0..3
    const bool tq0 = (lane & 1) != 0;     // tq bit0
    const bool tq1 = (lane & 2) != 0;     // tq bit1

    const float* vbase = Yb + (size_t)(ph * RS + pw) * OC3 + 2 * CIN + g * GOC + 4 * cq;

    f32x4 acc4 = {0.f, 0.f, 0.f, 0.f};

    auto attw = [&](auto jc) -> float {
        constexpr int j = decltype(jc)::value;
        constexpr int OFF = (((4 * j) & 31) << 5) | 0x03;   // BitMode: or=(4j)%32, and=3
        // j<8: value for tap t=tq+4j lives in lower half -> lower lanes use att,
        //      upper lanes use attB.  j>=8: swapped.
        float src = (hi ^ (j >= 8)) ? attB : att;
        return __int_as_float(__builtin_amdgcn_ds_swizzle(__float_as_int(src), OFF));
    };

    auto vstep = [&](auto jc) {
        constexpr int j = decltype(jc)::value;
        // per-lane doff for t = 4j + tq, selected from 4 compile-time consts
        int d01 = tq0 ? vdoff(4 * j + 1) : vdoff(4 * j + 0);
        int d23 = tq0 ? vdoff(4 * j + 3) : vdoff(4 * j + 2);
        int dof = tq1 ? d23 : d01;
        const f32x4 v4 = *(const f32x4*)(vbase + dof);
        float aj = attw(jc);
        #pragma unroll
        for (int cc = 0; cc < 4; ++cc)
            acc4[cc] = fmaf(aj, v4[cc], acc4[cc]);
    };

    vstep(IC<0>{});  vstep(IC<1>{});  vstep(IC<2>{});  vstep(IC<3>{});
    vstep(IC<4>{});  vstep(IC<5>{});  vstep(IC<6>{});  vstep(IC<7>{});
    vstep(IC<8>{});  vstep(IC<9>{});  vstep(IC<10>{}); vstep(IC<11>{});

    // tail tap 48 (t = 48 only valid for tq==0; att[49..51]==0 but their
    // addresses would leave the guarded region -> exec-mask the load)
    {
        float aj = attw(IC<12>{});
        if (tq == 0) {
            const f32x4 v4 = *(const f32x4*)(vbase + vdoff(48));
            #pragma unroll
            for (int cc = 0; cc < 4; ++cc)
                acc4[cc] = fmaf(aj, v4[cc], acc4[cc]);
        }
    }

    // reduce over the 4 tap classes (lanes differing in tq): xor1 + xor2
    #pragma unroll
    for (int cc = 0; cc < 4; ++cc) {
        float v = acc4[cc];
        v += xor_lane<1>(v);
        v += xor_lane<2>(v);
        acc4[cc] = v;
    }

    // lane L holds channels 4*(L>>2)..+3 (all tap classes reduced);
    // component (L&3) is exactly channel L.
    float outv = tq1 ? (tq0 ? acc4[3] : acc4[2]) : (tq0 ? acc4[1] : acc4[0]);

    xpose[w][lane] = outv;
    __syncthreads();
    const int wid0 = wblock * 4;
    const int pq0  = wid0 % PP;
    const int g0   = (wid0 / PP) & (NG - 1);
    const int b0   = wid0 / (PP * NG);
    const int ch   = tid >> 2;
    const int w2   = tid & 3;
    out[((size_t)b0 * 256 + g0 * GOC + ch) * PP + pq0 + w2] = xpose[w2][ch];
}

// ---------------------------------------------------------------------------
extern "C" void kernel_launch(void* const* d_in, const int* in_sizes, int n_in,
                              void* d_out, int out_size, void* d_ws, size_t ws_size,
                              hipStream_t stream)
{
    const float* x  = (const float*)d_in[0];
    const float* w  = (const float*)d_in[1];
    const float* rh = (const float*)d_in[2];
    const float* rw = (const float*)d_in[3];

    float* Y2 = (float*)d_ws;
    short* Xt = (short*)((char*)d_ws + XT_OFF);
    short* Wt = (short*)((char*)d_ws + WT_OFF);

    prep<<<2136, 256, 0, stream>>>(Y2, w, Wt, x, Xt);
    conv_mfma<<<dim3(36, 12, BB), 256, 0, stream>>>(Wt, Xt, Y2);
    attn_kernel<<<(BB * NG * PP) / 4, 256, 0, stream>>>(Y2, rh, rw, (float*)d_out);
}

// Round 4
// 110.587 us; speedup vs baseline: 1.1542x; 1.1542x over previous
//
#include <hip/hip_runtime.h>

// Problem constants
#define BB   2
#define CIN  256
#define OC3  768
#define NG   4
#define GOC  64
#define C2   32
#define KK   49
#define PP   2304
#define HALF_P 1152

// Guarded Y2 layout: rows -3..50 (54), cols -3..52 at stride 56, 768 ch.
#define RS      56
#define BROWS   54
#define BSTRIDE (BROWS * RS * OC3)          // floats per batch = 2,322,432
#define IOFF    ((3 * RS + 3) * OC3)

// Workspace layout (bytes)
#define Y2_BYTES  (BB * BROWS * RS * OC3 * 4)
#define XT_OFF    Y2_BYTES
#define WT_OFF    (XT_OFF + BB * PP * 512 * 2)

typedef __attribute__((ext_vector_type(8))) short bf16x8;
typedef __attribute__((ext_vector_type(4))) float f32x4;

static __device__ __forceinline__ unsigned short f2bf_rne(float x) {
    unsigned int u = __float_as_uint(x);
    unsigned int r = u + 0x7FFFu + ((u >> 16) & 1u);
    return (unsigned short)(r >> 16);
}
static __device__ __forceinline__ float bf2f(unsigned short h) {
    return __uint_as_float(((unsigned int)h) << 16);
}

// 16B global -> LDS direct staging (async; counted by vmcnt; drained by the
// compiler-emitted vmcnt(0) before s_barrier at __syncthreads()).
static __device__ __forceinline__ void gll16(const short* g, short* l) {
    __builtin_amdgcn_global_load_lds(
        (const __attribute__((address_space(1))) unsigned int*)g,
        (__attribute__((address_space(3))) unsigned int*)l,
        16, 0, 0);
}

// ---------------------------------------------------------------------------
// DPP-based exact xor-lane exchange (VALU pipe). Bit-identical semantics.
// ---------------------------------------------------------------------------
template <int C>
static __device__ __forceinline__ float dppf(float x) {
    return __int_as_float(__builtin_amdgcn_update_dpp(
        0, __float_as_int(x), C, 0xF, 0xF, true));
}
template <int D>
static __device__ __forceinline__ float xor_lane(float x) {
    if constexpr (D == 1)       return dppf<0xB1>(x);
    else if constexpr (D == 2)  return dppf<0x4E>(x);
    else if constexpr (D == 4)  return dppf<0x141>(dppf<0x4E>(dppf<0xB1>(x)));
    else if constexpr (D == 8)  return dppf<0x128>(x);
    else                        return __shfl_xor(x, D, 64);
}
template <int N> struct IC { static constexpr int value = N; };

// ---------------------------------------------------------------------------
// Fused prep kernel (unchanged).
// ---------------------------------------------------------------------------
#define ROW4  (RS * OC3 / 4)       // 10752 float4 per spatial row
#define REG1  (6 * ROW4)           // 6 full guard rows (0,1,2,51,52,53)
#define COLS4 (OC3 / 4)            // 192 float4 per cell

__global__ __launch_bounds__(256) void prep(
    float* __restrict__ Y2,
    const float* __restrict__ W, short* __restrict__ Wt,
    const float* __restrict__ X, short* __restrict__ Xt)
{
    __shared__ float tile[64][65];
    const int bid = blockIdx.x;
    const int t   = threadIdx.x;

    if (bid < 1080) {
        const int idx = (bid % 540) * 256 + t;      // 0 .. 138239
        const int b   = bid / 540;
        float4* Yb = (float4*)(Y2 + (size_t)b * BSTRIDE);
        const float4 z = make_float4(0.f, 0.f, 0.f, 0.f);
        if (idx < REG1) {
            int r6  = idx / ROW4;
            int rem = idx - r6 * ROW4;
            int r   = (r6 < 3) ? r6 : 48 + r6;      // 0,1,2,51,52,53
            Yb[r * ROW4 + rem] = z;
        } else {
            int i2  = idx - REG1;
            int r   = 3 + i2 / (8 * COLS4);         // 3..50
            int rem = i2 - (r - 3) * (8 * COLS4);
            int cg  = rem / COLS4;
            int c   = (cg < 3) ? cg : 48 + cg;      // 0,1,2,51..55
            int ch4 = rem - cg * COLS4;
            Yb[(r * RS + c) * COLS4 + ch4] = z;
        }
    } else if (bid < 1848) {
        int tt = (bid - 1080) * 256 + t;            // 0 .. 196607
        int o = tt >> 8, c = tt & 255;
        float v = W[tt];
        unsigned short hi = f2bf_rne(v);
        unsigned short lo = f2bf_rne(v - bf2f(hi));
        Wt[(size_t)o * 512 + c]       = (short)hi;
        Wt[(size_t)o * 512 + 256 + c] = (short)lo;
    } else {
        const int blk = bid - 1848;                 // 0 .. 287
        const int p0  = (blk % 36) * 64;
        const int c0  = ((blk / 36) & 3) * 64;
        const int b   = blk / 144;

        const float* Xb = X + (size_t)b * CIN * PP;
        #pragma unroll
        for (int r = 0; r < 16; ++r) {
            int idx = r * 256 + t;
            int c = idx >> 6, p = idx & 63;
            tile[c][p] = Xb[(size_t)(c0 + c) * PP + p0 + p];
        }
        __syncthreads();
        short* Xo = Xt + (size_t)b * PP * 512;
        #pragma unroll
        for (int r = 0; r < 16; ++r) {
            int idx = r * 256 + t;
            int p = idx >> 6, c = idx & 63;
            float v = tile[c][p];
            unsigned short hi = f2bf_rne(v);
            unsigned short lo = f2bf_rne(v - bf2f(hi));
            size_t base = (size_t)(p0 + p) * 512 + c0 + c;
            Xo[base]       = (short)hi;
            Xo[base + 256] = (short)lo;
        }
    }
}

// ---------------------------------------------------------------------------
// Kernel 1: conv as split-bf16 MFMA GEMM.
// r10: staging via global_load_lds width-16 (replaces reg+ds_write path).
// LDS is linear [64 rows][32 shorts] (gll writes lane*16B); bank conflicts
// on ds_read_b128 fixed by a 16B-slot XOR swizzle slot' = slot ^ ((row>>1)&3)
// applied BOTH on the per-lane global source address (inverse pre-swizzle)
// and the ds_read address (rule: both-sides-or-neither). Wave w stages its
// 16-row quarter of As and Bs (2 gll/wave/K-step). MFMA order and operand
// values unchanged -> bit-identical output.
// ---------------------------------------------------------------------------
__global__ __launch_bounds__(256, 4) void conv_mfma(
    const short* __restrict__ Wt,   // (768, 512)
    const short* __restrict__ Xt,   // (B, 2304, 512)
    float* __restrict__ Y2)
{
    __shared__ short As[64 * 32];   // [o][k] linear, slot-swizzled
    __shared__ short Bs[64 * 32];   // [p][k] linear, slot-swizzled

    const int tid = threadIdx.x;
    const int bn  = blockIdx.x;       // p tile (36)
    const int bm  = blockIdx.y;       // o tile (12)
    const int b   = blockIdx.z;
    const int om0 = bm * 64, pn0 = bn * 64;

    const int lane = tid & 63, w = tid >> 6;
    const int oq = (w & 1) * 32, pq = (w >> 1) * 32;
    const int ln15 = lane & 15, q = lane >> 4;

    // staging: wave w covers rows 16w..16w+15; lane L -> row 16w+L/4,
    // physical 16B slot L%4, which must receive data slot sd = (L%4)^((R>>1)&3)
    const int R  = (w << 4) + (lane >> 2);
    const int sd = (lane & 3) ^ ((R >> 1) & 3);
    const short* gAq = Wt + (size_t)(om0 + R) * 512 + sd * 8;
    const short* gBq = Xt + (size_t)b * PP * 512 + (size_t)(pn0 + R) * 512 + sd * 8;
    short* ldsA = As + w * 512;       // 16 rows * 32 shorts
    short* ldsB = Bs + w * 512;

    // read-side swizzle: row bits [2:1] == ln15 bits [2:1] for all frags
    const int swz = q ^ ((ln15 >> 1) & 3);

    f32x4 acc[2][2] = {};

    for (int k0 = 0; k0 < 768; k0 += 32) {
        const int wk = (k0 < 256) ? k0 : k0 - 256;   // W: hi, hi, lo
        const int xk = (k0 < 512) ? k0 : k0 - 512;   // X: hi, lo, hi
        __syncthreads();                 // previous tile's reads complete
        gll16(gAq + wk, ldsA);
        gll16(gBq + xk, ldsB);
        __syncthreads();                 // vmcnt(0) drain + barrier

        bf16x8 af[2], bf[2];
        #pragma unroll
        for (int i = 0; i < 2; ++i) {
            af[i] = *(const bf16x8*)&As[(oq + i * 16 + ln15) * 32 + swz * 8];
            bf[i] = *(const bf16x8*)&Bs[(pq + i * 16 + ln15) * 32 + swz * 8];
        }
        #pragma unroll
        for (int i = 0; i < 2; ++i)
            #pragma unroll
            for (int j = 0; j < 2; ++j)
                acc[i][j] = __builtin_amdgcn_mfma_f32_16x16x32_bf16(
                    af[i], bf[j], acc[i][j], 0, 0, 0);
    }

    // D[m=o][n=p]: lane = col p (ln15), rows o = q*4..q*4+3 contiguous
    float* Yb = Y2 + (size_t)b * BSTRIDE + IOFF;
    #pragma unroll
    for (int i = 0; i < 2; ++i) {
        #pragma unroll
        for (int j = 0; j < 2; ++j) {
            int o = om0 + oq + i * 16 + q * 4;
            int p = pn0 + pq + j * 16 + ln15;
            int h = p / 48, ww = p - h * 48;
            *(f32x4*)&Yb[(size_t)(h * RS + ww) * OC3 + o] = acc[i][j];
        }
    }
}

// ---------------------------------------------------------------------------
// Kernel 2: attention. One wave per (b,g,p'). XCD-swizzled.
// (r8/R2 version restored verbatim: streaming binary-tree reduction, DPP
// exchanges, scalar V loop. R3's vectorized V path regressed 15us -> reverted.)
// ---------------------------------------------------------------------------
struct TagH { static constexpr bool value = true;  };
struct TagW { static constexpr bool value = false; };

__global__ __launch_bounds__(256, 6) void attn_kernel(
    const float* __restrict__ Y2,
    const float* __restrict__ rpe_h,  // (4,1,7,1,32)
    const float* __restrict__ rpe_w,  // (4,1,1,7,32)
    float* __restrict__ out)          // (B, 256, 48, 48)
{
    __shared__ float xpose[4][65];

    const int tid  = threadIdx.x;
    const int lane = tid & 63;
    const int w    = tid >> 6;
    const int bx     = blockIdx.x;
    const int wblock = (bx & 7) * 576 + (bx >> 3);
    const int wid    = wblock * 4 + w;
    const int pq   = wid % PP;
    const int g    = (wid / PP) & (NG - 1);
    const int b    = wid / (PP * NG);
    const int ph   = pq / 48;
    const int pw   = pq - ph * 48;

    const float* Yb = Y2 + (size_t)b * BSTRIDE + IOFF;

    const float qv = Yb[(size_t)(ph * RS + pw) * OC3 + g * GOC + lane];

    const int t   = (pq >= HALF_P) ? 1 : 0;
    const int qpr = pq - t * HALF_P;
    const int p0  = 2 * qpr;
    const int ph0 = p0 / 48;
    const int pw0 = p0 - ph0 * 48;
    const int g2  = 2 * g + t;
    const bool use_h = (g2 < NG);
    const int  kch   = use_h ? (CIN + g2 * GOC) : (CIN + (g2 - NG) * GOC + C2);
    const float* rb  = use_h ? (rpe_h + g2 * 7 * C2) : (rpe_w + (g2 - NG) * 7 * C2);

    const int  c  = lane & 31;
    const bool hi = (lane >= 32);

    const float R0 = rb[0 * C2 + c], R1 = rb[1 * C2 + c], R2 = rb[2 * C2 + c],
                R3 = rb[3 * C2 + c], R4 = rb[4 * C2 + c], R5 = rb[5 * C2 + c],
                R6 = rb[6 * C2 + c];

    const float* kb = Yb + (size_t)(ph0 * RS + pw0) * OC3 + kch + c;

    auto rget = [&](int idx) -> float {
        return idx == 0 ? R0 : idx == 1 ? R1 : idx == 2 ? R2 :
               idx == 3 ? R3 : idx == 4 ? R4 : idx == 5 ? R5 : R6;
    };

    auto tree = [&](auto tag) -> float {
        constexpr bool UH = decltype(tag)::value;
        auto chunkprod = [&](int l) -> float {
            int m0 = 2 * l,     h10 = (m0 >= KK), k0 = m0 - KK * h10;
            int m1 = 2 * l + 1, h11 = (m1 >= KK), k1 = m1 - KK * h11;
            int i0 = k0 / 7, j0 = k0 % 7, i1 = k1 / 7, j1 = k1 % 7;
            int d0 = ((i0 - 3) * RS + (h10 + j0 - 3)) * OC3;
            int d1 = ((i1 - 3) * RS + (h11 + j1 - 3)) * OC3;
            float kv = kb[hi ? d1 : d0];
            float ra = UH ? rget(i0) : rget(j0);
            float rc = UH ? rget(i1) : rget(j1);
            kv += hi ? rc : ra;
            return qv * kv;
        };
        auto val = [&](int jj) -> float {
            if (2 * jj >= KK) return 0.f;
            float pa = chunkprod(2 * jj);
            float pb = (2 * jj + 1 < KK) ? chunkprod(2 * jj + 1) : 0.f;
            float u  = (lane & 1) ? pb : pa;
            float ww = (lane & 1) ? pa : pb;
            return u + xor_lane<1>(ww);
        };
        auto comb = [&](auto dc, float x, float y) -> float {
            constexpr int d = decltype(dc)::value;
            float u  = (lane & d) ? y : x;
            float ww = (lane & d) ? x : y;
            return u + xor_lane<d>(ww);
        };
        float acc32[2];
        #pragma unroll
        for (int a = 0; a < 2; ++a) {
            float acc16[2];
            #pragma unroll
            for (int bq = 0; bq < 2; ++bq) {
                float acc8[2];
                #pragma unroll
                for (int cq2 = 0; cq2 < 2; ++cq2) {
                    float acc4t[2];
                    #pragma unroll
                    for (int dq = 0; dq < 2; ++dq) {
                        float acc2[2];
                        #pragma unroll
                        for (int eq = 0; eq < 2; ++eq)
                            acc2[eq] = val(a * 16 + bq * 8 + cq2 * 4 + dq * 2 + eq);
                        acc4t[dq] = comb(IC<2>{}, acc2[0], acc2[1]);
                    }
                    acc8[cq2] = comb(IC<4>{}, acc4t[0], acc4t[1]);
                }
                acc16[bq] = comb(IC<8>{}, acc8[0], acc8[1]);
            }
            acc32[a] = comb(IC<16>{}, acc16[0], acc16[1]);
        }
        return comb(IC<32>{}, acc32[0], acc32[1]);
    };

    const float logit = use_h ? tree(TagH{}) : tree(TagW{});

    float mx = logit;
    mx = fmaxf(mx, xor_lane<1>(mx));
    mx = fmaxf(mx, xor_lane<2>(mx));
    mx = fmaxf(mx, xor_lane<4>(mx));
    mx = fmaxf(mx, xor_lane<8>(mx));
    mx = fmaxf(mx, xor_lane<16>(mx));
    mx = fmaxf(mx, xor_lane<32>(mx));
    float e = (lane < KK) ? __expf(logit - mx) : 0.f;
    float ssum = e;
    ssum += xor_lane<1>(ssum);
    ssum += xor_lane<2>(ssum);
    ssum += xor_lane<4>(ssum);
    ssum += xor_lane<8>(ssum);
    ssum += xor_lane<16>(ssum);
    ssum += xor_lane<32>(ssum);
    const float att = e / ssum;

    float acc = 0.f;
    const float* vb = Yb + (size_t)(ph * RS + pw) * OC3 + 2 * CIN + g * GOC + lane;
    #pragma unroll
    for (int k = 0; k < KK; ++k) {
        int i = k / 7, j = k % 7;
        int doff = ((i - 3) * RS + (j - 3)) * OC3;
        float ak = __uint_as_float(
            __builtin_amdgcn_readlane(__float_as_uint(att), k));
        acc = fmaf(ak, vb[doff], acc);
    }

    xpose[w][lane] = acc;
    __syncthreads();
    const int wid0 = wblock * 4;
    const int pq0  = wid0 % PP;
    const int g0   = (wid0 / PP) & (NG - 1);
    const int b0   = wid0 / (PP * NG);
    const int ch   = tid >> 2;
    const int w2   = tid & 3;
    out[((size_t)b0 * 256 + g0 * GOC + ch) * PP + pq0 + w2] = xpose[w2][ch];
}

// ---------------------------------------------------------------------------
extern "C" void kernel_launch(void* const* d_in, const int* in_sizes, int n_in,
                              void* d_out, int out_size, void* d_ws, size_t ws_size,
                              hipStream_t stream)
{
    const float* x  = (const float*)d_in[0];
    const float* w  = (const float*)d_in[1];
    const float* rh = (const float*)d_in[2];
    const float* rw = (const float*)d_in[3];

    float* Y2 = (float*)d_ws;
    short* Xt = (short*)((char*)d_ws + XT_OFF);
    short* Wt = (short*)((char*)d_ws + WT_OFF);

    prep<<<2136, 256, 0, stream>>>(Y2, w, Wt, x, Xt);
    conv_mfma<<<dim3(36, 12, BB), 256, 0, stream>>>(Wt, Xt, Y2);
    attn_kernel<<<(BB * NG * PP) / 4, 256, 0, stream>>>(Y2, rh, rw, (float*)d_out);
}

// Round 5
// 109.422 us; speedup vs baseline: 1.1665x; 1.0107x over previous
//
#include <hip/hip_runtime.h>

// Problem constants
#define BB   2
#define CIN  256
#define OC3  768
#define NG   4
#define GOC  64
#define C2   32
#define KK   49
#define PP   2304
#define HALF_P 1152

// Guarded Y2 layout: rows -3..50 (54), cols -3..52 at stride 56, 768 ch.
#define RS      56
#define BROWS   54
#define BSTRIDE (BROWS * RS * OC3)          // floats per batch = 2,322,432
#define IOFF    ((3 * RS + 3) * OC3)

// Workspace layout (bytes)
#define Y2_BYTES  (BB * BROWS * RS * OC3 * 4)
#define XT_OFF    Y2_BYTES
#define WT_OFF    (XT_OFF + BB * PP * 512 * 2)

typedef __attribute__((ext_vector_type(8))) short bf16x8;
typedef __attribute__((ext_vector_type(4))) float f32x4;

static __device__ __forceinline__ unsigned short f2bf_rne(float x) {
    unsigned int u = __float_as_uint(x);
    unsigned int r = u + 0x7FFFu + ((u >> 16) & 1u);
    return (unsigned short)(r >> 16);
}
static __device__ __forceinline__ float bf2f(unsigned short h) {
    return __uint_as_float(((unsigned int)h) << 16);
}

// 16B global -> LDS direct staging (async; counted by vmcnt; drained by the
// compiler-emitted vmcnt(0) before s_barrier at __syncthreads()).
static __device__ __forceinline__ void gll16(const short* g, short* l) {
    __builtin_amdgcn_global_load_lds(
        (const __attribute__((address_space(1))) unsigned int*)g,
        (__attribute__((address_space(3))) unsigned int*)l,
        16, 0, 0);
}

// ---------------------------------------------------------------------------
// DPP-based exact xor-lane exchange (VALU pipe). Bit-identical semantics.
// ---------------------------------------------------------------------------
template <int C>
static __device__ __forceinline__ float dppf(float x) {
    return __int_as_float(__builtin_amdgcn_update_dpp(
        0, __float_as_int(x), C, 0xF, 0xF, true));
}
template <int D>
static __device__ __forceinline__ float xor_lane(float x) {
    if constexpr (D == 1)       return dppf<0xB1>(x);
    else if constexpr (D == 2)  return dppf<0x4E>(x);
    else if constexpr (D == 4)  return dppf<0x141>(dppf<0x4E>(dppf<0xB1>(x)));
    else if constexpr (D == 8)  return dppf<0x128>(x);
    else                        return __shfl_xor(x, D, 64);
}
template <int N> struct IC { static constexpr int value = N; };

// ---------------------------------------------------------------------------
// prep: converts only (zero_guard relocated into conv_mfma's grid, r11).
// blocks 0..767: convert_w ; 768..1055: convert_x.
// ---------------------------------------------------------------------------
#define ROW4  (RS * OC3 / 4)       // 10752 float4 per spatial row
#define REG1  (6 * ROW4)           // 6 full guard rows (0,1,2,51,52,53)
#define COLS4 (OC3 / 4)            // 192 float4 per cell

__global__ __launch_bounds__(256) void prep(
    const float* __restrict__ W, short* __restrict__ Wt,
    const float* __restrict__ X, short* __restrict__ Xt)
{
    __shared__ float tile[64][65];
    const int bid = blockIdx.x;
    const int t   = threadIdx.x;

    if (bid < 768) {
        // ---- convert_w: W (768,256) fp32 -> Wt (768,512) bf16 hi|lo ----
        int tt = bid * 256 + t;                     // 0 .. 196607
        int o = tt >> 8, c = tt & 255;
        float v = W[tt];
        unsigned short hi = f2bf_rne(v);
        unsigned short lo = f2bf_rne(v - bf2f(hi));
        Wt[(size_t)o * 512 + c]       = (short)hi;
        Wt[(size_t)o * 512 + 256 + c] = (short)lo;
    } else {
        // ---- convert_x: X (B,256,2304) fp32 -> Xt (B,2304,512) bf16 hi|lo
        const int blk = bid - 768;                  // 0 .. 287
        const int p0  = (blk % 36) * 64;
        const int c0  = ((blk / 36) & 3) * 64;
        const int b   = blk / 144;

        const float* Xb = X + (size_t)b * CIN * PP;
        #pragma unroll
        for (int r = 0; r < 16; ++r) {
            int idx = r * 256 + t;
            int c = idx >> 6, p = idx & 63;
            tile[c][p] = Xb[(size_t)(c0 + c) * PP + p0 + p];
        }
        __syncthreads();
        short* Xo = Xt + (size_t)b * PP * 512;
        #pragma unroll
        for (int r = 0; r < 16; ++r) {
            int idx = r * 256 + t;
            int p = idx >> 6, c = idx & 63;
            float v = tile[c][p];
            unsigned short hi = f2bf_rne(v);
            unsigned short lo = f2bf_rne(v - bf2f(hi));
            size_t base = (size_t)(p0 + p) * 512 + c0 + c;
            Xo[base]       = (short)hi;
            Xo[base + 256] = (short)lo;
        }
    }
}

// ---------------------------------------------------------------------------
// Kernel 1: conv as split-bf16 MFMA GEMM + relocated zero_guard blocks.
// r11: (a) 2-phase software pipeline: double-buffered LDS; iteration t issues
// the STAGE for tile t+1 into buf[cur^1] BEFORE the MFMA of buf[cur]; one
// __syncthreads per K-step (was two) -- stage latency hides under
// ds_read+MFMA.  Race argument: iter-t stage targets the buffer read at
// t-1; every wave passed the t-1 end barrier before any wave issues iter-t
// stages, and the t-end barrier's vmcnt(0) drain publishes the staged data
// before t+1 reads it.  MFMA order/operands unchanged -> bit-identical Y2.
// (b) bm in [12,27): zero_guard body (disjoint writes from GEMM interior;
// consumed only by attn) -- overlaps the guard fill with the GEMM.
// ---------------------------------------------------------------------------
__global__ __launch_bounds__(256, 4) void conv_mfma(
    const short* __restrict__ Wt,   // (768, 512)
    const short* __restrict__ Xt,   // (B, 2304, 512)
    float* __restrict__ Y2)
{
    __shared__ short As[2][64 * 32];   // [buf][o][k] linear, slot-swizzled
    __shared__ short Bs[2][64 * 32];   // [buf][p][k]

    const int tid = threadIdx.x;
    const int bn  = blockIdx.x;       // p tile (36)
    const int bm  = blockIdx.y;       // o tile (12) or guard plane (12..26)
    const int b   = blockIdx.z;

    if (bm >= 12) {
        // ---- relocated zero_guard: zero only the guard cells of Y2 ----
        const int idx = ((bm - 12) * 36 + bn) * 256 + tid;   // 0 .. 138239
        float4* Yb = (float4*)(Y2 + (size_t)b * BSTRIDE);
        const float4 z = make_float4(0.f, 0.f, 0.f, 0.f);
        if (idx < REG1) {
            int r6  = idx / ROW4;
            int rem = idx - r6 * ROW4;
            int r   = (r6 < 3) ? r6 : 48 + r6;      // 0,1,2,51,52,53
            Yb[r * ROW4 + rem] = z;
        } else {
            int i2  = idx - REG1;
            int r   = 3 + i2 / (8 * COLS4);         // 3..50
            int rem = i2 - (r - 3) * (8 * COLS4);
            int cg  = rem / COLS4;
            int c   = (cg < 3) ? cg : 48 + cg;      // 0,1,2,51..55
            int ch4 = rem - cg * COLS4;
            Yb[(r * RS + c) * COLS4 + ch4] = z;
        }
        return;
    }

    const int om0 = bm * 64, pn0 = bn * 64;

    const int lane = tid & 63, w = tid >> 6;
    const int oq = (w & 1) * 32, pq = (w >> 1) * 32;
    const int ln15 = lane & 15, q = lane >> 4;

    // staging: wave w covers rows 16w..16w+15; lane L -> row 16w+L/4,
    // physical 16B slot L%4 receives data slot sd = (L%4)^((R>>1)&3)
    const int R  = (w << 4) + (lane >> 2);
    const int sd = (lane & 3) ^ ((R >> 1) & 3);
    const short* gAq = Wt + (size_t)(om0 + R) * 512 + sd * 8;
    const short* gBq = Xt + (size_t)b * PP * 512 + (size_t)(pn0 + R) * 512 + sd * 8;

    // read-side swizzle
    const int swz = q ^ ((ln15 >> 1) & 3);

    f32x4 acc[2][2] = {};

    // prologue: stage tile 0 into buf 0
    gll16(gAq + 0, &As[0][w * 512]);
    gll16(gBq + 0, &Bs[0][w * 512]);
    __syncthreads();

    for (int t = 0; t < 24; ++t) {
        const int cur = t & 1;

        bf16x8 af[2], bf[2];
        #pragma unroll
        for (int i = 0; i < 2; ++i) {
            af[i] = *(const bf16x8*)&As[cur][(oq + i * 16 + ln15) * 32 + swz * 8];
            bf[i] = *(const bf16x8*)&Bs[cur][(pq + i * 16 + ln15) * 32 + swz * 8];
        }

        if (t < 23) {
            const int k0 = 32 * (t + 1);
            const int wk = (k0 < 256) ? k0 : k0 - 256;   // W: hi, hi, lo
            const int xk = (k0 < 512) ? k0 : k0 - 512;   // X: hi, lo, hi
            gll16(gAq + wk, &As[cur ^ 1][w * 512]);
            gll16(gBq + xk, &Bs[cur ^ 1][w * 512]);
        }

        #pragma unroll
        for (int i = 0; i < 2; ++i)
            #pragma unroll
            for (int j = 0; j < 2; ++j)
                acc[i][j] = __builtin_amdgcn_mfma_f32_16x16x32_bf16(
                    af[i], bf[j], acc[i][j], 0, 0, 0);

        if (t < 23) __syncthreads();   // drains stage (vmcnt0) + read fence
    }

    // D[m=o][n=p]: lane = col p (ln15), rows o = q*4..q*4+3 contiguous
    float* Yb = Y2 + (size_t)b * BSTRIDE + IOFF;
    #pragma unroll
    for (int i = 0; i < 2; ++i) {
        #pragma unroll
        for (int j = 0; j < 2; ++j) {
            int o = om0 + oq + i * 16 + q * 4;
            int p = pn0 + pq + j * 16 + ln15;
            int h = p / 48, ww = p - h * 48;
            *(f32x4*)&Yb[(size_t)(h * RS + ww) * OC3 + o] = acc[i][j];
        }
    }
}

// ---------------------------------------------------------------------------
// Kernel 2: attention. One wave per (b,g,p'). XCD-swizzled. (unchanged, R4)
// ---------------------------------------------------------------------------
struct TagH { static constexpr bool value = true;  };
struct TagW { static constexpr bool value = false; };

__global__ __launch_bounds__(256, 6) void attn_kernel(
    const float* __restrict__ Y2,
    const float* __restrict__ rpe_h,  // (4,1,7,1,32)
    const float* __restrict__ rpe_w,  // (4,1,1,7,32)
    float* __restrict__ out)          // (B, 256, 48, 48)
{
    __shared__ float xpose[4][65];

    const int tid  = threadIdx.x;
    const int lane = tid & 63;
    const int w    = tid >> 6;
    const int bx     = blockIdx.x;
    const int wblock = (bx & 7) * 576 + (bx >> 3);
    const int wid    = wblock * 4 + w;
    const int pq   = wid % PP;
    const int g    = (wid / PP) & (NG - 1);
    const int b    = wid / (PP * NG);
    const int ph   = pq / 48;
    const int pw   = pq - ph * 48;

    const float* Yb = Y2 + (size_t)b * BSTRIDE + IOFF;

    const float qv = Yb[(size_t)(ph * RS + pw) * OC3 + g * GOC + lane];

    const int t   = (pq >= HALF_P) ? 1 : 0;
    const int qpr = pq - t * HALF_P;
    const int p0  = 2 * qpr;
    const int ph0 = p0 / 48;
    const int pw0 = p0 - ph0 * 48;
    const int g2  = 2 * g + t;
    const bool use_h = (g2 < NG);
    const int  kch   = use_h ? (CIN + g2 * GOC) : (CIN + (g2 - NG) * GOC + C2);
    const float* rb  = use_h ? (rpe_h + g2 * 7 * C2) : (rpe_w + (g2 - NG) * 7 * C2);

    const int  c  = lane & 31;
    const bool hi = (lane >= 32);

    const float R0 = rb[0 * C2 + c], R1 = rb[1 * C2 + c], R2 = rb[2 * C2 + c],
                R3 = rb[3 * C2 + c], R4 = rb[4 * C2 + c], R5 = rb[5 * C2 + c],
                R6 = rb[6 * C2 + c];

    const float* kb = Yb + (size_t)(ph0 * RS + pw0) * OC3 + kch + c;

    auto rget = [&](int idx) -> float {
        return idx == 0 ? R0 : idx == 1 ? R1 : idx == 2 ? R2 :
               idx == 3 ? R3 : idx == 4 ? R4 : idx == 5 ? R5 : R6;
    };

    auto tree = [&](auto tag) -> float {
        constexpr bool UH = decltype(tag)::value;
        auto chunkprod = [&](int l) -> float {
            int m0 = 2 * l,     h10 = (m0 >= KK), k0 = m0 - KK * h10;
            int m1 = 2 * l + 1, h11 = (m1 >= KK), k1 = m1 - KK * h11;
            int i0 = k0 / 7, j0 = k0 % 7, i1 = k1 / 7, j1 = k1 % 7;
            int d0 = ((i0 - 3) * RS + (h10 + j0 - 3)) * OC3;
            int d1 = ((i1 - 3) * RS + (h11 + j1 - 3)) * OC3;
            float kv = kb[hi ? d1 : d0];
            float ra = UH ? rget(i0) : rget(j0);
            float rc = UH ? rget(i1) : rget(j1);
            kv += hi ? rc : ra;
            return qv * kv;
        };
        auto val = [&](int jj) -> float {
            if (2 * jj >= KK) return 0.f;
            float pa = chunkprod(2 * jj);
            float pb = (2 * jj + 1 < KK) ? chunkprod(2 * jj + 1) : 0.f;
            float u  = (lane & 1) ? pb : pa;
            float ww = (lane & 1) ? pa : pb;
            return u + xor_lane<1>(ww);
        };
        auto comb = [&](auto dc, float x, float y) -> float {
            constexpr int d = decltype(dc)::value;
            float u  = (lane & d) ? y : x;
            float ww = (lane & d) ? x : y;
            return u + xor_lane<d>(ww);
        };
        float acc32[2];
        #pragma unroll
        for (int a = 0; a < 2; ++a) {
            float acc16[2];
            #pragma unroll
            for (int bq = 0; bq < 2; ++bq) {
                float acc8[2];
                #pragma unroll
                for (int cq2 = 0; cq2 < 2; ++cq2) {
                    float acc4t[2];
                    #pragma unroll
                    for (int dq = 0; dq < 2; ++dq) {
                        float acc2[2];
                        #pragma unroll
                        for (int eq = 0; eq < 2; ++eq)
                            acc2[eq] = val(a * 16 + bq * 8 + cq2 * 4 + dq * 2 + eq);
                        acc4t[dq] = comb(IC<2>{}, acc2[0], acc2[1]);
                    }
                    acc8[cq2] = comb(IC<4>{}, acc4t[0], acc4t[1]);
                }
                acc16[bq] = comb(IC<8>{}, acc8[0], acc8[1]);
            }
            acc32[a] = comb(IC<16>{}, acc16[0], acc16[1]);
        }
        return comb(IC<32>{}, acc32[0], acc32[1]);
    };

    const float logit = use_h ? tree(TagH{}) : tree(TagW{});

    float mx = logit;
    mx = fmaxf(mx, xor_lane<1>(mx));
    mx = fmaxf(mx, xor_lane<2>(mx));
    mx = fmaxf(mx, xor_lane<4>(mx));
    mx = fmaxf(mx, xor_lane<8>(mx));
    mx = fmaxf(mx, xor_lane<16>(mx));
    mx = fmaxf(mx, xor_lane<32>(mx));
    float e = (lane < KK) ? __expf(logit - mx) : 0.f;
    float ssum = e;
    ssum += xor_lane<1>(ssum);
    ssum += xor_lane<2>(ssum);
    ssum += xor_lane<4>(ssum);
    ssum += xor_lane<8>(ssum);
    ssum += xor_lane<16>(ssum);
    ssum += xor_lane<32>(ssum);
    const float att = e / ssum;

    float acc = 0.f;
    const float* vb = Yb + (size_t)(ph * RS + pw) * OC3 + 2 * CIN + g * GOC + lane;
    #pragma unroll
    for (int k = 0; k < KK; ++k) {
        int i = k / 7, j = k % 7;
        int doff = ((i - 3) * RS + (j - 3)) * OC3;
        float ak = __uint_as_float(
            __builtin_amdgcn_readlane(__float_as_uint(att), k));
        acc = fmaf(ak, vb[doff], acc);
    }

    xpose[w][lane] = acc;
    __syncthreads();
    const int wid0 = wblock * 4;
    const int pq0  = wid0 % PP;
    const int g0   = (wid0 / PP) & (NG - 1);
    const int b0   = wid0 / (PP * NG);
    const int ch   = tid >> 2;
    const int w2   = tid & 3;
    out[((size_t)b0 * 256 + g0 * GOC + ch) * PP + pq0 + w2] = xpose[w2][ch];
}

// ---------------------------------------------------------------------------
extern "C" void kernel_launch(void* const* d_in, const int* in_sizes, int n_in,
                              void* d_out, int out_size, void* d_ws, size_t ws_size,
                              hipStream_t stream)
{
    const float* x  = (const float*)d_in[0];
    const float* w  = (const float*)d_in[1];
    const float* rh = (const float*)d_in[2];
    const float* rw = (const float*)d_in[3];

    float* Y2 = (float*)d_ws;
    short* Xt = (short*)((char*)d_ws + XT_OFF);
    short* Wt = (short*)((char*)d_ws + WT_OFF);

    prep<<<1056, 256, 0, stream>>>(w, Wt, x, Xt);
    // bm 0..11: GEMM o-tiles; bm 12..26: relocated zero_guard (15*36*2=1080)
    conv_mfma<<<dim3(36, 27, BB), 256, 0, stream>>>(Wt, Xt, Y2);
    attn_kernel<<<(BB * NG * PP) / 4, 256, 0, stream>>>(Y2, rh, rw, (float*)d_out);
}